// Round 7
// baseline (108.756 us; speedup 1.0000x reference)
//
#include <hip/hip_runtime.h>

#define NQ 12
#define NSTATES 4096          // 2^12
#define NLAYERS 4
#define NGATES 48             // 12 merged (RY·Rot_l0) + 3*12 Rot
#define NGROUPS 12            // 4 commuting gates per pass
#define TPB 256

// ---------------------------------------------------------------------------
// Compile-time gate schedule. CNOTs are never executed: we track the GF(2)
// map A with phys[j] == ref[A*j].  CNOT(c,t): rows[bt]^=rows[bc] (rows of A),
// bcols[bc]^=bcols[bt] (cols of A^-1).  1q gate on logical bit b pairs
// phys {j, j^bcols[b]}, |0>-role where parity(j & rows[b])==0.
// Z_w expval sign = (-1)^parity(j & rows[11-w]).
// Embedding RY(x_w) and layer-0 Rot on wire w are fused into one SU(2) gate
// (adjacent in the reference, A = I at that point).
// ---------------------------------------------------------------------------
struct Sched { unsigned m[NGATES]; unsigned sel[NGATES]; unsigned zrow[NQ]; };

constexpr Sched make_sched() {
    Sched s{};
    unsigned rows[NQ] = {}, bcols[NQ] = {};
    for (int b = 0; b < NQ; ++b) { rows[b] = 1u << b; bcols[b] = 1u << b; }
    int g = 0;
    // merged RY+Rot(layer0) on wires 0..11, A = I
    for (int w = 0; w < NQ; ++w) { int b = NQ - 1 - w; s.m[g] = bcols[b]; s.sel[g] = rows[b]; ++g; }
    for (int l = 0; l < NLAYERS; ++l) {
        if (l > 0)
            for (int w = 0; w < NQ; ++w) { int b = NQ - 1 - w; s.m[g] = bcols[b]; s.sel[g] = rows[b]; ++g; }
        int r = (l % (NQ - 1)) + 1;
        for (int w = 0; w < NQ; ++w) {
            int c = w, t = (w + r) % NQ;
            int bc = NQ - 1 - c, bt = NQ - 1 - t;
            rows[bt] ^= rows[bc];
            bcols[bc] ^= bcols[bt];
        }
    }
    for (int w = 0; w < NQ; ++w) s.zrow[w] = rows[NQ - 1 - w];
    return s;
}

// LDS slot swizzle: fold high nibbles into the bank nibble; GF(2)-linear.
constexpr unsigned swz(unsigned j) { return j ^ (((j >> 4) ^ (j >> 8)) & 0xFu); }

struct Group {
    unsigned sel[4];       // parity masks per gate
    unsigned swzc[16];     // swz(cmask[e]), cmask[e] = XOR of masks chosen by e
    unsigned cparbits[4];  // bit e = parity(cmask[e] & sel[i])
    int npos[8];           // non-pivot bit positions (ascending) for coset reps
};
struct Plan {
    Group g[NGROUPS];
    unsigned zrow[NQ];
    unsigned zparbits[NQ]; // bit e = parity(cmask_last[e] & zrow[w])
};

constexpr bool inv4(const unsigned m[4], int p0, int p1, int p2, int p3) {
    int pv[4] = {p0, p1, p2, p3};
    unsigned rows[4] = {};
    for (int i = 0; i < 4; ++i) {
        unsigned r = 0;
        for (int k = 0; k < 4; ++k) r |= ((m[i] >> pv[k]) & 1u) << k;
        rows[i] = r;
    }
    unsigned used = 0; int rank = 0;
    for (int c = 0; c < 4; ++c) {
        int pr = -1;
        for (int r = 0; r < 4; ++r)
            if (!((used >> r) & 1u) && ((rows[r] >> c) & 1u)) { pr = r; break; }
        if (pr < 0) continue;
        used |= 1u << pr; ++rank;
        for (int r = 0; r < 4; ++r)
            if (r != pr && ((rows[r] >> c) & 1u)) rows[r] ^= rows[pr];
    }
    return rank == 4;
}

constexpr int popc12(unsigned v) { int c = 0; for (int i = 0; i < 12; ++i) c += (v >> i) & 1; return c; }
constexpr int msb12(unsigned v) { int m = -1; for (int i = 0; i < 12; ++i) if ((v >> i) & 1) m = i; return m; }

// residue-class coverage (mod 4) of the 6 lowest non-pivot positions; 4 = ideal
// (lane bit at position p feeds swizzled-slot bank bit (p & 3); full coverage
// => 64 lanes spread exactly 4-per-bank-pair on every ds_*_b64 => conflict-free)
constexpr int coverage(const int piv[4]) {
    bool isp[12] = {};
    for (int i = 0; i < 4; ++i) isp[piv[i]] = true;
    bool seen[4] = {}; int cov = 0, cnt = 0;
    for (int p = 0; p < 12 && cnt < 6; ++p)
        if (!isp[p]) { if (!seen[p & 3]) { seen[p & 3] = true; ++cov; } ++cnt; }
    return cov;
}

constexpr Plan make_plan() {
    Sched s = make_sched();
    Plan pl{};
    for (int w = 0; w < NQ; ++w) pl.zrow[w] = s.zrow[w];
    for (int gi = 0; gi < NGROUPS; ++gi) {
        Group &G = pl.g[gi];
        unsigned m[4] = {};
        for (int i = 0; i < 4; ++i) { m[i] = s.m[gi * 4 + i]; G.sel[i] = s.sel[gi * 4 + i]; }
        int piv[4] = {};
        unsigned bas[4] = {};
        for (int i = 0; i < 4; ++i) {
            unsigned v = m[i];
            for (int k = 0; k < i; ++k) if ((v >> piv[k]) & 1u) v ^= bas[k];
            piv[i] = msb12(v);
            bas[i] = v;
        }
        if (coverage(piv) < 4) {  // repair: single pivot swaps for bank coverage
            int best[4] = {piv[0], piv[1], piv[2], piv[3]};
            int bestcov = coverage(piv);
            for (int a = 0; a < 4 && bestcov < 4; ++a) {
                for (int q = 0; q < 12 && bestcov < 4; ++q) {
                    bool dup = false;
                    for (int i = 0; i < 4; ++i) if (piv[i] == q) dup = true;
                    if (dup) continue;
                    int cand[4] = {piv[0], piv[1], piv[2], piv[3]};
                    cand[a] = q;
                    if (!inv4(m, cand[0], cand[1], cand[2], cand[3])) continue;
                    int cv = coverage(cand);
                    if (cv > bestcov) { bestcov = cv; for (int i = 0; i < 4; ++i) best[i] = cand[i]; }
                }
            }
            for (int i = 0; i < 4; ++i) piv[i] = best[i];
        }
        {
            bool isp[12] = {};
            for (int i = 0; i < 4; ++i) isp[piv[i]] = true;
            int k = 0;
            for (int p = 0; p < 12; ++p) if (!isp[p]) G.npos[k++] = p;
        }
        for (int e = 0; e < 16; ++e) {
            unsigned c = 0;
            for (int q = 0; q < 4; ++q) if ((e >> q) & 1) c ^= m[q];
            G.swzc[e] = swz(c);
        }
        for (int i = 0; i < 4; ++i) {
            unsigned bits = 0;
            for (int e = 0; e < 16; ++e) {
                unsigned c = 0;
                for (int q = 0; q < 4; ++q) if ((e >> q) & 1) c ^= m[q];
                if (popc12(c & G.sel[i]) & 1) bits |= 1u << e;
            }
            G.cparbits[i] = bits;
        }
        if (gi == NGROUPS - 1) {
            for (int w = 0; w < NQ; ++w) {
                unsigned bits = 0;
                for (int e = 0; e < 16; ++e) {
                    unsigned c = 0;
                    for (int q = 0; q < 4; ++q) if ((e >> q) & 1) c ^= m[q];
                    if (popc12(c & s.zrow[w]) & 1) bits |= 1u << e;
                }
                pl.zparbits[w] = bits;
            }
        }
    }
    return pl;
}

// __device__ so the epilogue's ODR-uses (runtime-indexed before unrolling)
// are unambiguously legal in device code; all folds to immediates anyway.
__device__ constexpr Plan PLAN = make_plan();

__device__ __forceinline__ float xorf(float a, unsigned s) {
    return __uint_as_float(__float_as_uint(a) ^ s);
}

// ---------------------------------------------------------------------------
// One pass: thread owns one 16-element XOR-coset of the group's 4 masks,
// applies the 4 SU(2) gates in registers. template<GI> guarantees every
// mask / swizzle / parity bit is an instruction immediate.
// Gate [[u,v],[-v*,u*]]; role-1 element uses (u,v)->(u*,-v*): sign of ui,vr.
// sign = per-gate runtime parity (sgP) XOR compile-time coset bit -> both
// signed variants precomputed per gate, selected per-e at compile time.
// Pair-role flip across each pair is guaranteed: parity(m_i & sel_i) =
// (A * A^-1)_bb = 1.
// Cosets partition the 4096 slots bijectively per group, so each slot has
// exactly one reader+writer per pass: one barrier per seam is sufficient.
// ---------------------------------------------------------------------------
template <int GI>
__device__ __forceinline__ void do_pass(int tid, float (&ar)[16], float (&ai)[16],
                                        unsigned &jr_out, float2* st, const float4* gmat)
{
    constexpr Group G = PLAN.g[GI];

    unsigned jr = 0;
    #pragma unroll
    for (int k = 0; k < 8; ++k) jr |= ((unsigned)(tid >> k) & 1u) << G.npos[k];
    const unsigned basev = jr ^ (((jr >> 4) ^ (jr >> 8)) & 0xFu);   // swz(jr)

    if constexpr (GI == 0) {
        #pragma unroll
        for (int e = 0; e < 16; ++e) { ar[e] = 0.0f; ai[e] = 0.0f; }
        if (jr == 0u) ar[0] = 1.0f;            // |0...0>, cmask[0]==0
    } else {
        #pragma unroll
        for (int e = 0; e < 16; ++e) {
            float2 v = st[basev ^ G.swzc[e]];
            ar[e] = v.x; ai[e] = v.y;
        }
    }

    #pragma unroll
    for (int i = 0; i < 4; ++i) {
        const float4 uv = gmat[GI * 4 + i];
        const unsigned sgP = (unsigned)(__popc(jr & G.sel[i]) & 1) << 31;
        const float ur = uv.x, vi = uv.w;
        const float ui_p = xorf(uv.y, sgP), ui_n = xorf(uv.y, sgP ^ 0x80000000u);
        const float vr_p = xorf(uv.z, sgP), vr_n = xorf(uv.z, sgP ^ 0x80000000u);
        #pragma unroll
        for (int e = 0; e < 16; ++e) {
            if (e & (1 << i)) continue;
            const int f = e | (1 << i);
            const bool neg = ((G.cparbits[i] >> e) & 1u) != 0;   // compile-time
            const float ui = neg ? ui_n : ui_p;
            const float vr = neg ? vr_n : vr_p;
            const float xr_ = ar[e], xi_ = ai[e];
            const float yr_ = ar[f], yi_ = ai[f];
            ar[e] = ur * xr_ - ui * xi_ + vr * yr_ - vi * yi_;
            ai[e] = ur * xi_ + ui * xr_ + vr * yi_ + vi * yr_;
            ar[f] = ur * yr_ + ui * yi_ - vr * xr_ - vi * xi_;
            ai[f] = ur * yi_ - ui * yr_ - vr * xi_ + vi * xr_;
        }
    }

    if constexpr (GI < NGROUPS - 1) {
        #pragma unroll
        for (int e = 0; e < 16; ++e)
            st[basev ^ G.swzc[e]] = make_float2(ar[e], ai[e]);
        __syncthreads();
    }
    jr_out = jr;
}

template <int GI>
__device__ __forceinline__ void run_from(int tid, float (&ar)[16], float (&ai)[16],
                                         unsigned &jr, float2* st, const float4* gmat)
{
    do_pass<GI>(tid, ar, ai, jr, st, gmat);
    if constexpr (GI + 1 < NGROUPS) run_from<GI + 1>(tid, ar, ai, jr, st, gmat);
}

__global__ __launch_bounds__(TPB, 4) void qreg_kernel(
    const float* __restrict__ x,    // (B, 12)
    const float* __restrict__ W,    // (4, 12, 3)
    const float* __restrict__ hw,   // (1, 12)
    const float* __restrict__ hb,   // (1,)
    float* __restrict__ out)        // (B,)
{
    __shared__ float2 st[NSTATES];   // 32 KB state (swizzled slots)
    __shared__ float4 gmat[NGATES];  // (ur, ui, vr, vi)
    __shared__ float red[TPB / 64];

    const int tid = threadIdx.x;
    const int b = blockIdx.x;

    // ---- gate matrices: one thread per gate -------------------------------
    if (tid < NGATES) {
        const int l = tid / NQ;          // 0 = merged layer, 1..3 = Rot layers 1..3
        const int w = tid % NQ;
        const float* wp = W + tid * 3;   // W[l, w, :]
        float phi = wp[0], th = wp[1], om = wp[2];
        float sn, cs;  sincosf(0.5f * th, &sn, &cs);
        float sa, ca;  sincosf(0.5f * (phi + om), &sa, &ca);
        float sb, cb;  sincosf(0.5f * (phi - om), &sb, &cb);
        float u2r = ca * cs, u2i = -sa * cs;   // u = e^{-i(phi+om)/2} cos
        float v2r = -cb * sn, v2i = -sb * sn;  // v = -e^{ i(phi-om)/2} sin
        float ur, ui, vr, vi;
        if (l == 0) {
            // fuse RY(x[b,w]) before: u' = u2*c1 + v2*s1 ; v' = v2*c1 - u2*s1
            float s1, c1; sincosf(0.5f * x[b * NQ + w], &s1, &c1);
            ur = u2r * c1 + v2r * s1;  ui = u2i * c1 + v2i * s1;
            vr = v2r * c1 - u2r * s1;  vi = v2i * c1 - u2i * s1;
        } else {
            ur = u2r; ui = u2i; vr = v2r; vi = v2i;
        }
        gmat[tid] = make_float4(ur, ui, vr, vi);
    }
    __syncthreads();

    // ---- 12 register-blocked passes (4 gates each) ------------------------
    float ar[16], ai[16];
    unsigned jr = 0;
    run_from<0>(tid, ar, ai, jr, st, gmat);

    // ---- fused Z expvals + linear head (state still in registers) ---------
    float hws[NQ];
    #pragma unroll
    for (int w = 0; w < NQ; ++w) {
        const unsigned sg = (unsigned)(__popc(jr & PLAN.zrow[w]) & 1) << 31;
        hws[w] = xorf(hw[w], sg);
    }
    float acc = 0.0f;
    #pragma unroll
    for (int e = 0; e < 16; ++e) {
        const float prob = ar[e] * ar[e] + ai[e] * ai[e];
        float coef = 0.0f;
        #pragma unroll
        for (int w = 0; w < NQ; ++w)
            coef += ((PLAN.zparbits[w] >> e) & 1u) ? -hws[w] : hws[w];  // compile-time sel
        acc += prob * coef;
    }

    #pragma unroll
    for (int o = 32; o > 0; o >>= 1) acc += __shfl_xor(acc, o, 64);
    if ((tid & 63) == 0) red[tid >> 6] = acc;
    __syncthreads();
    if (tid == 0) out[b] = red[0] + red[1] + red[2] + red[3] + hb[0];
}

extern "C" void kernel_launch(void* const* d_in, const int* in_sizes, int n_in,
                              void* d_out, int out_size, void* d_ws, size_t ws_size,
                              hipStream_t stream) {
    const float* x  = (const float*)d_in[0];   // (B, 12) float32
    const float* W  = (const float*)d_in[1];   // (4, 12, 3) float32
    const float* hw = (const float*)d_in[2];   // (1, 12) float32
    const float* hb = (const float*)d_in[3];   // (1,) float32
    float* out = (float*)d_out;                // (B,) float32

    int B = in_sizes[0] / NQ;                  // 1024
    qreg_kernel<<<B, TPB, 0, stream>>>(x, W, hw, hb, out);
}

// Round 9
// 92.515 us; speedup vs baseline: 1.1756x; 1.1756x over previous
//
#include <hip/hip_runtime.h>

#define NQ 12
#define NSTATES 4096          // 2^12
#define NLAYERS 4
#define NGATES 48             // 12 merged (RY·Rot_l0) + 3*12 Rot
#define NGROUPS 12            // 4 commuting gates per pass
#define TPB 256

// ---------------------------------------------------------------------------
// Compile-time gate schedule. CNOTs are never executed: we track the GF(2)
// map A with phys[j] == ref[A*j].  CNOT(c,t): rows[bt]^=rows[bc] (rows of A),
// bcols[bc]^=bcols[bt] (cols of A^-1).  1q gate on logical bit b pairs
// phys {j, j^bcols[b]}, |0>-role where parity(j & rows[b])==0.
// Z_w expval sign = (-1)^parity(j & rows[11-w]).
// Embedding RY(x_w) and layer-0 Rot on wire w are fused into one SU(2) gate
// (adjacent in the reference, A = I at that point).
// ---------------------------------------------------------------------------
struct Sched { unsigned m[NGATES]; unsigned sel[NGATES]; unsigned zrow[NQ]; };

constexpr Sched make_sched() {
    Sched s{};
    unsigned rows[NQ] = {}, bcols[NQ] = {};
    for (int b = 0; b < NQ; ++b) { rows[b] = 1u << b; bcols[b] = 1u << b; }
    int g = 0;
    // merged RY+Rot(layer0) on wires 0..11, A = I
    for (int w = 0; w < NQ; ++w) { int b = NQ - 1 - w; s.m[g] = bcols[b]; s.sel[g] = rows[b]; ++g; }
    for (int l = 0; l < NLAYERS; ++l) {
        if (l > 0)
            for (int w = 0; w < NQ; ++w) { int b = NQ - 1 - w; s.m[g] = bcols[b]; s.sel[g] = rows[b]; ++g; }
        int r = (l % (NQ - 1)) + 1;
        for (int w = 0; w < NQ; ++w) {
            int c = w, t = (w + r) % NQ;
            int bc = NQ - 1 - c, bt = NQ - 1 - t;
            rows[bt] ^= rows[bc];
            bcols[bc] ^= bcols[bt];
        }
    }
    for (int w = 0; w < NQ; ++w) s.zrow[w] = rows[NQ - 1 - w];
    return s;
}

// LDS slot swizzle: fold high nibbles into the bank nibble; GF(2)-linear.
constexpr unsigned swz(unsigned j) { return j ^ (((j >> 4) ^ (j >> 8)) & 0xFu); }

struct Group {
    unsigned sel[4];       // parity masks per gate
    unsigned swzc[16];     // swz(cmask[e]), cmask[e] = XOR of masks chosen by e
    unsigned cparbits[4];  // bit e = parity(cmask[e] & sel[i])
    int npos[8];           // non-pivot bit positions (ascending) for coset reps
};
struct Plan {
    Group g[NGROUPS];
    unsigned zrow[NQ];
    unsigned zparbits[NQ]; // bit e = parity(cmask_last[e] & zrow[w])
};

constexpr bool inv4(const unsigned m[4], int p0, int p1, int p2, int p3) {
    int pv[4] = {p0, p1, p2, p3};
    unsigned rows[4] = {};
    for (int i = 0; i < 4; ++i) {
        unsigned r = 0;
        for (int k = 0; k < 4; ++k) r |= ((m[i] >> pv[k]) & 1u) << k;
        rows[i] = r;
    }
    unsigned used = 0; int rank = 0;
    for (int c = 0; c < 4; ++c) {
        int pr = -1;
        for (int r = 0; r < 4; ++r)
            if (!((used >> r) & 1u) && ((rows[r] >> c) & 1u)) { pr = r; break; }
        if (pr < 0) continue;
        used |= 1u << pr; ++rank;
        for (int r = 0; r < 4; ++r)
            if (r != pr && ((rows[r] >> c) & 1u)) rows[r] ^= rows[pr];
    }
    return rank == 4;
}

constexpr int popc12(unsigned v) { int c = 0; for (int i = 0; i < 12; ++i) c += (v >> i) & 1; return c; }
constexpr int msb12(unsigned v) { int m = -1; for (int i = 0; i < 12; ++i) if ((v >> i) & 1) m = i; return m; }

// residue-class coverage (mod 4) of the 6 lowest non-pivot positions; 4 = ideal
// (lane bit at position p feeds swizzled-slot bank bit (p & 3); full coverage
// => 64 lanes spread exactly 4-per-bank-pair on every ds_*_b64 => conflict-free)
// HW-verified round 7: SQ_LDS_BANK_CONFLICT = 512/block ~ 0.5% of ds ops.
constexpr int coverage(const int piv[4]) {
    bool isp[12] = {};
    for (int i = 0; i < 4; ++i) isp[piv[i]] = true;
    bool seen[4] = {}; int cov = 0, cnt = 0;
    for (int p = 0; p < 12 && cnt < 6; ++p)
        if (!isp[p]) { if (!seen[p & 3]) { seen[p & 3] = true; ++cov; } ++cnt; }
    return cov;
}

constexpr Plan make_plan() {
    Sched s = make_sched();
    Plan pl{};
    for (int w = 0; w < NQ; ++w) pl.zrow[w] = s.zrow[w];
    for (int gi = 0; gi < NGROUPS; ++gi) {
        Group &G = pl.g[gi];
        unsigned m[4] = {};
        for (int i = 0; i < 4; ++i) { m[i] = s.m[gi * 4 + i]; G.sel[i] = s.sel[gi * 4 + i]; }
        int piv[4] = {};
        unsigned bas[4] = {};
        for (int i = 0; i < 4; ++i) {
            unsigned v = m[i];
            for (int k = 0; k < i; ++k) if ((v >> piv[k]) & 1u) v ^= bas[k];
            piv[i] = msb12(v);
            bas[i] = v;
        }
        if (coverage(piv) < 4) {  // repair: single pivot swaps for bank coverage
            int best[4] = {piv[0], piv[1], piv[2], piv[3]};
            int bestcov = coverage(piv);
            for (int a = 0; a < 4 && bestcov < 4; ++a) {
                for (int q = 0; q < 12 && bestcov < 4; ++q) {
                    bool dup = false;
                    for (int i = 0; i < 4; ++i) if (piv[i] == q) dup = true;
                    if (dup) continue;
                    int cand[4] = {piv[0], piv[1], piv[2], piv[3]};
                    cand[a] = q;
                    if (!inv4(m, cand[0], cand[1], cand[2], cand[3])) continue;
                    int cv = coverage(cand);
                    if (cv > bestcov) { bestcov = cv; for (int i = 0; i < 4; ++i) best[i] = cand[i]; }
                }
            }
            for (int i = 0; i < 4; ++i) piv[i] = best[i];
        }
        {
            bool isp[12] = {};
            for (int i = 0; i < 4; ++i) isp[piv[i]] = true;
            int k = 0;
            for (int p = 0; p < 12; ++p) if (!isp[p]) G.npos[k++] = p;
        }
        for (int e = 0; e < 16; ++e) {
            unsigned c = 0;
            for (int q = 0; q < 4; ++q) if ((e >> q) & 1) c ^= m[q];
            G.swzc[e] = swz(c);
        }
        for (int i = 0; i < 4; ++i) {
            unsigned bits = 0;
            for (int e = 0; e < 16; ++e) {
                unsigned c = 0;
                for (int q = 0; q < 4; ++q) if ((e >> q) & 1) c ^= m[q];
                if (popc12(c & G.sel[i]) & 1) bits |= 1u << e;
            }
            G.cparbits[i] = bits;
        }
        if (gi == NGROUPS - 1) {
            for (int w = 0; w < NQ; ++w) {
                unsigned bits = 0;
                for (int e = 0; e < 16; ++e) {
                    unsigned c = 0;
                    for (int q = 0; q < 4; ++q) if ((e >> q) & 1) c ^= m[q];
                    if (popc12(c & s.zrow[w]) & 1) bits |= 1u << e;
                }
                pl.zparbits[w] = bits;
            }
        }
    }
    return pl;
}

// __device__ so the epilogue's ODR-uses (runtime-indexed before unrolling)
// are unambiguously legal in device code; all folds to immediates anyway.
__device__ constexpr Plan PLAN = make_plan();

__device__ __forceinline__ float xorf(float a, unsigned s) {
    return __uint_as_float(__float_as_uint(a) ^ s);
}

// ---------------------------------------------------------------------------
// One pass: thread owns one 16-element XOR-coset of the group's 4 masks,
// applies the 4 SU(2) gates in registers. template<GI> guarantees every
// mask / swizzle / parity bit is an instruction immediate.
// Gate [[u,v],[-v*,u*]]; role-1 element uses (u,v)->(u*,-v*): sign of ui,vr.
// All complex-mul terms written as explicit fmaf (1 mul + 3 fma per
// component; sign flips become free source modifiers).
// ---------------------------------------------------------------------------
template <int GI>
__device__ __forceinline__ void do_pass(int tid, float (&ar)[16], float (&ai)[16],
                                        unsigned &jr_out, float2* st, const float4* gmat)
{
    constexpr Group G = PLAN.g[GI];

    unsigned jr = 0;
    #pragma unroll
    for (int k = 0; k < 8; ++k) jr |= ((unsigned)(tid >> k) & 1u) << G.npos[k];
    const unsigned basev = jr ^ (((jr >> 4) ^ (jr >> 8)) & 0xFu);   // swz(jr)

    if constexpr (GI == 0) {
        #pragma unroll
        for (int e = 0; e < 16; ++e) { ar[e] = 0.0f; ai[e] = 0.0f; }
        if (jr == 0u) ar[0] = 1.0f;            // |0...0>, cmask[0]==0
    } else {
        #pragma unroll
        for (int e = 0; e < 16; ++e) {
            float2 v = st[basev ^ G.swzc[e]];
            ar[e] = v.x; ai[e] = v.y;
        }
    }

    #pragma unroll
    for (int i = 0; i < 4; ++i) {
        const float4 uv = gmat[GI * 4 + i];
        const unsigned sgP = (unsigned)(__popc(jr & G.sel[i]) & 1) << 31;
        const float ur = uv.x, vi = uv.w;
        const float ui_p = xorf(uv.y, sgP), ui_n = xorf(uv.y, sgP ^ 0x80000000u);
        const float vr_p = xorf(uv.z, sgP), vr_n = xorf(uv.z, sgP ^ 0x80000000u);
        #pragma unroll
        for (int e = 0; e < 16; ++e) {
            if (e & (1 << i)) continue;
            const int f = e | (1 << i);
            const bool neg = ((G.cparbits[i] >> e) & 1u) != 0;   // compile-time
            const float ui = neg ? ui_n : ui_p;
            const float vr = neg ? vr_n : vr_p;
            const float xr_ = ar[e], xi_ = ai[e];
            const float yr_ = ar[f], yi_ = ai[f];
            // n0 = u*x + v*y ; n1 = conj(u)*y - conj(v)*x  (role signs in ui,vr)
            ar[e] = fmaf(ur, xr_, fmaf(-ui, xi_, fmaf(vr, yr_, -vi * yi_)));
            ai[e] = fmaf(ur, xi_, fmaf( ui, xr_, fmaf(vr, yi_,  vi * yr_)));
            ar[f] = fmaf(ur, yr_, fmaf( ui, yi_, fmaf(-vr, xr_, -vi * xi_)));
            ai[f] = fmaf(ur, yi_, fmaf(-ui, yr_, fmaf(-vr, xi_,  vi * xr_)));
        }
    }

    if constexpr (GI < NGROUPS - 1) {
        #pragma unroll
        for (int e = 0; e < 16; ++e)
            st[basev ^ G.swzc[e]] = make_float2(ar[e], ai[e]);
        __syncthreads();
    }
    jr_out = jr;
}

template <int GI>
__device__ __forceinline__ void run_from(int tid, float (&ar)[16], float (&ai)[16],
                                         unsigned &jr, float2* st, const float4* gmat)
{
    do_pass<GI>(tid, ar, ai, jr, st, gmat);
    if constexpr (GI + 1 < NGROUPS) run_from<GI + 1>(tid, ar, ai, jr, st, gmat);
}

// waves_per_eu(4,4): LDS (33 KB/block) caps residency at 4 blocks/CU = 4
// waves/EU anyway; round-7 HW data shows the default heuristic targeted 8
// waves/EU, capped VGPRs at 64, and spilled ~80 B/thread (20.9 MB scratch
// writes/dispatch). Pinning max=4 gives the allocator the full 128-VGPR
// budget -> no spill, same occupancy.
__global__ __launch_bounds__(TPB)
__attribute__((amdgpu_waves_per_eu(4, 4)))
void qreg_kernel(
    const float* __restrict__ x,    // (B, 12)
    const float* __restrict__ W,    // (4, 12, 3)
    const float* __restrict__ hw,   // (1, 12)
    const float* __restrict__ hb,   // (1,)
    float* __restrict__ out)        // (B,)
{
    __shared__ float2 st[NSTATES];   // 32 KB state (swizzled slots)
    __shared__ float4 gmat[NGATES];  // (ur, ui, vr, vi)
    __shared__ float red[TPB / 64];

    const int tid = threadIdx.x;
    const int b = blockIdx.x;

    // ---- gate matrices: one thread per gate -------------------------------
    if (tid < NGATES) {
        const int l = tid / NQ;          // 0 = merged layer, 1..3 = Rot layers 1..3
        const int w = tid % NQ;
        const float* wp = W + tid * 3;   // W[l, w, :]
        float phi = wp[0], th = wp[1], om = wp[2];
        float sn, cs;  sincosf(0.5f * th, &sn, &cs);
        float sa, ca;  sincosf(0.5f * (phi + om), &sa, &ca);
        float sb, cb;  sincosf(0.5f * (phi - om), &sb, &cb);
        float u2r = ca * cs, u2i = -sa * cs;   // u = e^{-i(phi+om)/2} cos
        float v2r = -cb * sn, v2i = -sb * sn;  // v = -e^{ i(phi-om)/2} sin
        float ur, ui, vr, vi;
        if (l == 0) {
            // fuse RY(x[b,w]) before: u' = u2*c1 + v2*s1 ; v' = v2*c1 - u2*s1
            float s1, c1; sincosf(0.5f * x[b * NQ + w], &s1, &c1);
            ur = u2r * c1 + v2r * s1;  ui = u2i * c1 + v2i * s1;
            vr = v2r * c1 - u2r * s1;  vi = v2i * c1 - u2i * s1;
        } else {
            ur = u2r; ui = u2i; vr = v2r; vi = v2i;
        }
        gmat[tid] = make_float4(ur, ui, vr, vi);
    }
    __syncthreads();

    // ---- 12 register-blocked passes (4 gates each) ------------------------
    float ar[16], ai[16];
    unsigned jr = 0;
    run_from<0>(tid, ar, ai, jr, st, gmat);

    // ---- fused Z expvals + linear head (state still in registers) ---------
    float hws[NQ];
    #pragma unroll
    for (int w = 0; w < NQ; ++w) {
        const unsigned sg = (unsigned)(__popc(jr & PLAN.zrow[w]) & 1) << 31;
        hws[w] = xorf(hw[w], sg);
    }
    float acc = 0.0f;
    #pragma unroll
    for (int e = 0; e < 16; ++e) {
        const float prob = fmaf(ar[e], ar[e], ai[e] * ai[e]);
        float coef = 0.0f;
        #pragma unroll
        for (int w = 0; w < NQ; ++w)
            coef += ((PLAN.zparbits[w] >> e) & 1u) ? -hws[w] : hws[w];  // compile-time sel
        acc = fmaf(prob, coef, acc);
    }

    #pragma unroll
    for (int o = 32; o > 0; o >>= 1) acc += __shfl_xor(acc, o, 64);
    if ((tid & 63) == 0) red[tid >> 6] = acc;
    __syncthreads();
    if (tid == 0) out[b] = red[0] + red[1] + red[2] + red[3] + hb[0];
}

extern "C" void kernel_launch(void* const* d_in, const int* in_sizes, int n_in,
                              void* d_out, int out_size, void* d_ws, size_t ws_size,
                              hipStream_t stream) {
    const float* x  = (const float*)d_in[0];   // (B, 12) float32
    const float* W  = (const float*)d_in[1];   // (4, 12, 3) float32
    const float* hw = (const float*)d_in[2];   // (1, 12) float32
    const float* hb = (const float*)d_in[3];   // (1,) float32
    float* out = (float*)d_out;                // (B,) float32

    int B = in_sizes[0] / NQ;                  // 1024
    qreg_kernel<<<B, TPB, 0, stream>>>(x, W, hw, hb, out);
}

// Round 13
// 88.454 us; speedup vs baseline: 1.2295x; 1.0459x over previous
//
#include <hip/hip_runtime.h>

#define NQ 12
#define NSTATES 4096          // 2^12
#define NLAYERS 4
#define NGATES 48             // 12 merged (RY·Rot_l0) + 3*12 Rot
#define NMERGED 12            // merged gates folded into product-state init
#define NGROUPS 9             // butterfly passes over gates 12..47, 4 per pass
#define TPB 256

// ---------------------------------------------------------------------------
// CNOTs are never executed: GF(2) map A with phys[j] == ref[A*j].
// CNOT(c,t): rows[bt]^=rows[bc] (rows of A), bcols[bc]^=bcols[bt] (cols of
// A^-1). 1q gate on logical bit b pairs phys {j, j^bcols[b]}, |0>-role where
// parity(j & rows[b])==0.  Z_w sign = (-1)^parity(j & rows[11-w]).
// The 12 merged RY+Rot_l0 gates act on |0...0> BEFORE any CNOT -> state is a
// PRODUCT state amp(j) = prod_w f_w(bit_w(j)), f_w(0)=u_w, f_w(1)=-conj(v_w).
// Built directly in ~150 fma; butterfly passes start at gate 12.
// ---------------------------------------------------------------------------
struct Sched { unsigned m[NGATES]; unsigned sel[NGATES]; unsigned zrow[NQ]; };

constexpr Sched make_sched() {
    Sched s{};
    unsigned rows[NQ] = {}, bcols[NQ] = {};
    for (int b = 0; b < NQ; ++b) { rows[b] = 1u << b; bcols[b] = 1u << b; }
    int g = 0;
    for (int w = 0; w < NQ; ++w) { int b = NQ - 1 - w; s.m[g] = bcols[b]; s.sel[g] = rows[b]; ++g; }
    for (int l = 0; l < NLAYERS; ++l) {
        if (l > 0)
            for (int w = 0; w < NQ; ++w) { int b = NQ - 1 - w; s.m[g] = bcols[b]; s.sel[g] = rows[b]; ++g; }
        int r = (l % (NQ - 1)) + 1;
        for (int w = 0; w < NQ; ++w) {
            int c = w, t = (w + r) % NQ;
            int bc = NQ - 1 - c, bt = NQ - 1 - t;
            rows[bt] ^= rows[bc];
            bcols[bc] ^= bcols[bt];
        }
    }
    for (int w = 0; w < NQ; ++w) s.zrow[w] = rows[NQ - 1 - w];
    return s;
}

// LDS slot swizzle: fold high nibbles into the bank nibble; GF(2)-linear.
// HW-verified (r7/r9): SQ_LDS_BANK_CONFLICT ~0.5% of ds ops with this + the
// pivot-coverage repair below.
constexpr unsigned swz(unsigned j) { return j ^ (((j >> 4) ^ (j >> 8)) & 0xFu); }

struct Group {
    unsigned sel[4];
    unsigned swzc[16];
    unsigned cparbits[4];
    int npos[8];
};
struct Plan {
    Group g[NGROUPS];
    unsigned zrow[NQ];
    unsigned zparbits[NQ];
};

constexpr bool inv4(const unsigned m[4], int p0, int p1, int p2, int p3) {
    int pv[4] = {p0, p1, p2, p3};
    unsigned rows[4] = {};
    for (int i = 0; i < 4; ++i) {
        unsigned r = 0;
        for (int k = 0; k < 4; ++k) r |= ((m[i] >> pv[k]) & 1u) << k;
        rows[i] = r;
    }
    unsigned used = 0; int rank = 0;
    for (int c = 0; c < 4; ++c) {
        int pr = -1;
        for (int r = 0; r < 4; ++r)
            if (!((used >> r) & 1u) && ((rows[r] >> c) & 1u)) { pr = r; break; }
        if (pr < 0) continue;
        used |= 1u << pr; ++rank;
        for (int r = 0; r < 4; ++r)
            if (r != pr && ((rows[r] >> c) & 1u)) rows[r] ^= rows[pr];
    }
    return rank == 4;
}

constexpr int popc12(unsigned v) { int c = 0; for (int i = 0; i < 12; ++i) c += (v >> i) & 1; return c; }
constexpr int msb12(unsigned v) { int m = -1; for (int i = 0; i < 12; ++i) if ((v >> i) & 1) m = i; return m; }

constexpr int coverage(const int piv[4]) {
    bool isp[12] = {};
    for (int i = 0; i < 4; ++i) isp[piv[i]] = true;
    bool seen[4] = {}; int cov = 0, cnt = 0;
    for (int p = 0; p < 12 && cnt < 6; ++p)
        if (!isp[p]) { if (!seen[p & 3]) { seen[p & 3] = true; ++cov; } ++cnt; }
    return cov;
}

constexpr Plan make_plan() {
    Sched s = make_sched();
    Plan pl{};
    for (int w = 0; w < NQ; ++w) pl.zrow[w] = s.zrow[w];
    for (int gi = 0; gi < NGROUPS; ++gi) {
        Group &G = pl.g[gi];
        unsigned m[4] = {};
        for (int i = 0; i < 4; ++i) {
            m[i] = s.m[NMERGED + gi * 4 + i];
            G.sel[i] = s.sel[NMERGED + gi * 4 + i];
        }
        int piv[4] = {};
        unsigned bas[4] = {};
        for (int i = 0; i < 4; ++i) {
            unsigned v = m[i];
            for (int k = 0; k < i; ++k) if ((v >> piv[k]) & 1u) v ^= bas[k];
            piv[i] = msb12(v);
            bas[i] = v;
        }
        if (coverage(piv) < 4) {
            int best[4] = {piv[0], piv[1], piv[2], piv[3]};
            int bestcov = coverage(piv);
            for (int a = 0; a < 4 && bestcov < 4; ++a) {
                for (int q = 0; q < 12 && bestcov < 4; ++q) {
                    bool dup = false;
                    for (int i = 0; i < 4; ++i) if (piv[i] == q) dup = true;
                    if (dup) continue;
                    int cand[4] = {piv[0], piv[1], piv[2], piv[3]};
                    cand[a] = q;
                    if (!inv4(m, cand[0], cand[1], cand[2], cand[3])) continue;
                    int cv = coverage(cand);
                    if (cv > bestcov) { bestcov = cv; for (int i = 0; i < 4; ++i) best[i] = cand[i]; }
                }
            }
            for (int i = 0; i < 4; ++i) piv[i] = best[i];
        }
        {
            bool isp[12] = {};
            for (int i = 0; i < 4; ++i) isp[piv[i]] = true;
            int k = 0;
            for (int p = 0; p < 12; ++p) if (!isp[p]) G.npos[k++] = p;
        }
        for (int e = 0; e < 16; ++e) {
            unsigned c = 0;
            for (int q = 0; q < 4; ++q) if ((e >> q) & 1) c ^= m[q];
            G.swzc[e] = swz(c);
        }
        for (int i = 0; i < 4; ++i) {
            unsigned bits = 0;
            for (int e = 0; e < 16; ++e) {
                unsigned c = 0;
                for (int q = 0; q < 4; ++q) if ((e >> q) & 1) c ^= m[q];
                if (popc12(c & G.sel[i]) & 1) bits |= 1u << e;
            }
            G.cparbits[i] = bits;
        }
        if (gi == NGROUPS - 1) {
            for (int w = 0; w < NQ; ++w) {
                unsigned bits = 0;
                for (int e = 0; e < 16; ++e) {
                    unsigned c = 0;
                    for (int q = 0; q < 4; ++q) if ((e >> q) & 1) c ^= m[q];
                    if (popc12(c & s.zrow[w]) & 1) bits |= 1u << e;
                }
                pl.zparbits[w] = bits;
            }
        }
    }
    return pl;
}

__device__ constexpr Plan PLAN = make_plan();

__device__ __forceinline__ float xorf(float a, unsigned s) {
    return __uint_as_float(__float_as_uint(a) ^ s);
}

// ---------------------------------------------------------------------------
// One butterfly pass (gates NMERGED+GI*4 .. +3). Loads are split 8/8 with
// gate-0 butterflies interleaved so the second load batch overlaps compute
// (finer lgkmcnt waits). Gate [[u,v],[-v*,u*]]; role-1 uses (u*,-v*).
// ---------------------------------------------------------------------------
template <int GI>
__device__ __forceinline__ void do_pass(int tid, float (&ar)[16], float (&ai)[16],
                                        unsigned &jr_out, float2* st, const float4* gmat)
{
    constexpr Group G = PLAN.g[GI];

    unsigned jr = 0;
    #pragma unroll
    for (int k = 0; k < 8; ++k) jr |= ((unsigned)(tid >> k) & 1u) << G.npos[k];
    const unsigned basev = jr ^ (((jr >> 4) ^ (jr >> 8)) & 0xFu);   // swz(jr)

    // ---- first 8 loads ----------------------------------------------------
    #pragma unroll
    for (int e = 0; e < 8; ++e) {
        float2 v = st[basev ^ G.swzc[e]];
        ar[e] = v.x; ai[e] = v.y;
    }

    // ---- gate 0: butterflies on loaded half, overlap second-half loads ----
    {
        const float4 uv = gmat[NMERGED + GI * 4 + 0];
        const unsigned sgP = (unsigned)(__popc(jr & G.sel[0]) & 1) << 31;
        const float ur = uv.x, vi = uv.w;
        const float ui_p = xorf(uv.y, sgP), ui_n = xorf(uv.y, sgP ^ 0x80000000u);
        const float vr_p = xorf(uv.z, sgP), vr_n = xorf(uv.z, sgP ^ 0x80000000u);
        #pragma unroll
        for (int e = 0; e < 8; e += 2) {
            const int f = e | 1;
            const bool neg = ((G.cparbits[0] >> e) & 1u) != 0;
            const float ui = neg ? ui_n : ui_p;
            const float vr = neg ? vr_n : vr_p;
            const float xr_ = ar[e], xi_ = ai[e];
            const float yr_ = ar[f], yi_ = ai[f];
            ar[e] = fmaf(ur, xr_, fmaf(-ui, xi_, fmaf(vr, yr_, -vi * yi_)));
            ai[e] = fmaf(ur, xi_, fmaf( ui, xr_, fmaf(vr, yi_,  vi * yr_)));
            ar[f] = fmaf(ur, yr_, fmaf( ui, yi_, fmaf(-vr, xr_, -vi * xi_)));
            ai[f] = fmaf(ur, yi_, fmaf(-ui, yr_, fmaf(-vr, xi_,  vi * xr_)));
        }
        #pragma unroll
        for (int e = 8; e < 16; ++e) {
            float2 v = st[basev ^ G.swzc[e]];
            ar[e] = v.x; ai[e] = v.y;
        }
        #pragma unroll
        for (int e = 8; e < 16; e += 2) {
            const int f = e | 1;
            const bool neg = ((G.cparbits[0] >> e) & 1u) != 0;
            const float ui = neg ? ui_n : ui_p;
            const float vr = neg ? vr_n : vr_p;
            const float xr_ = ar[e], xi_ = ai[e];
            const float yr_ = ar[f], yi_ = ai[f];
            ar[e] = fmaf(ur, xr_, fmaf(-ui, xi_, fmaf(vr, yr_, -vi * yi_)));
            ai[e] = fmaf(ur, xi_, fmaf( ui, xr_, fmaf(vr, yi_,  vi * yr_)));
            ar[f] = fmaf(ur, yr_, fmaf( ui, yi_, fmaf(-vr, xr_, -vi * xi_)));
            ai[f] = fmaf(ur, yi_, fmaf(-ui, yr_, fmaf(-vr, xi_,  vi * xr_)));
        }
    }

    // ---- gates 1..3 -------------------------------------------------------
    #pragma unroll
    for (int i = 1; i < 4; ++i) {
        const float4 uv = gmat[NMERGED + GI * 4 + i];
        const unsigned sgP = (unsigned)(__popc(jr & G.sel[i]) & 1) << 31;
        const float ur = uv.x, vi = uv.w;
        const float ui_p = xorf(uv.y, sgP), ui_n = xorf(uv.y, sgP ^ 0x80000000u);
        const float vr_p = xorf(uv.z, sgP), vr_n = xorf(uv.z, sgP ^ 0x80000000u);
        #pragma unroll
        for (int e = 0; e < 16; ++e) {
            if (e & (1 << i)) continue;
            const int f = e | (1 << i);
            const bool neg = ((G.cparbits[i] >> e) & 1u) != 0;
            const float ui = neg ? ui_n : ui_p;
            const float vr = neg ? vr_n : vr_p;
            const float xr_ = ar[e], xi_ = ai[e];
            const float yr_ = ar[f], yi_ = ai[f];
            ar[e] = fmaf(ur, xr_, fmaf(-ui, xi_, fmaf(vr, yr_, -vi * yi_)));
            ai[e] = fmaf(ur, xi_, fmaf( ui, xr_, fmaf(vr, yi_,  vi * yr_)));
            ar[f] = fmaf(ur, yr_, fmaf( ui, yi_, fmaf(-vr, xr_, -vi * xi_)));
            ai[f] = fmaf(ur, yi_, fmaf(-ui, yr_, fmaf(-vr, xi_,  vi * xr_)));
        }
    }

    if constexpr (GI < NGROUPS - 1) {
        #pragma unroll
        for (int e = 0; e < 16; ++e)
            st[basev ^ G.swzc[e]] = make_float2(ar[e], ai[e]);
        __syncthreads();
    }
    jr_out = jr;
}

template <int GI>
__device__ __forceinline__ void run_from(int tid, float (&ar)[16], float (&ai)[16],
                                         unsigned &jr, float2* st, const float4* gmat)
{
    do_pass<GI>(tid, ar, ai, jr, st, gmat);
    if constexpr (GI + 1 < NGROUPS) run_from<GI + 1>(tid, ar, ai, jr, st, gmat);
}

// waves_per_eu(4,4): LDS caps residency at 4 blocks/CU = 4 waves/EU; pinning
// max=4 gives the 128-VGPR budget. HW-verified r9: spill eliminated
// (WRITE_SIZE 20.9 MB -> 32 KB), VGPR 60.
__global__ __launch_bounds__(TPB)
__attribute__((amdgpu_waves_per_eu(4, 4)))
void qreg_kernel(
    const float* __restrict__ x,    // (B, 12)
    const float* __restrict__ W,    // (4, 12, 3)
    const float* __restrict__ hw,   // (1, 12)
    const float* __restrict__ hb,   // (1,)
    float* __restrict__ out)        // (B,)
{
    __shared__ float2 st[NSTATES];   // 32 KB state (swizzled slots)
    __shared__ float4 gmat[NGATES];  // (ur, ui, vr, vi)
    __shared__ float red[TPB / 64];

    const int tid = threadIdx.x;
    const int b = blockIdx.x;

    // ---- gate matrices: one thread per gate -------------------------------
    if (tid < NGATES) {
        const int l = tid / NQ;
        const int w = tid % NQ;
        const float* wp = W + tid * 3;
        float phi = wp[0], th = wp[1], om = wp[2];
        float sn, cs;  sincosf(0.5f * th, &sn, &cs);
        float sa, ca;  sincosf(0.5f * (phi + om), &sa, &ca);
        float sb, cb;  sincosf(0.5f * (phi - om), &sb, &cb);
        float u2r = ca * cs, u2i = -sa * cs;
        float v2r = -cb * sn, v2i = -sb * sn;
        float ur, ui, vr, vi;
        if (l == 0) {
            float s1, c1; sincosf(0.5f * x[b * NQ + w], &s1, &c1);
            ur = u2r * c1 + v2r * s1;  ui = u2i * c1 + v2i * s1;
            vr = v2r * c1 - u2r * s1;  vi = v2i * c1 - u2i * s1;
        } else {
            ur = u2r; ui = u2i; vr = v2r; vi = v2i;
        }
        gmat[tid] = make_float4(ur, ui, vr, vi);
    }
    __syncthreads();

    float ar[16], ai[16];

    // ---- product-state init (replaces first 3 butterfly passes) -----------
    // amp(j) = prod_p f(gmat[11-p], bit_p(j)), j = (tid<<4)|e.
    // f(g,0) = (g.x, g.y); f(g,1) = (-g.z, g.w)   [= -conj(v)]
    {
        float pr = 1.0f, pi = 0.0f;                  // prefix over tid bits
        #pragma unroll
        for (int k = 7; k >= 0; --k) {               // bit p=k+4 -> gmat[7-k]
            const float4 g = gmat[7 - k];
            const bool bset = ((tid >> k) & 1) != 0;
            const float fr = bset ? -g.z : g.x;
            const float fi = bset ?  g.w : g.y;
            const float nr = fmaf(pr, fr, -pi * fi);
            const float ni = fmaf(pr, fi,  pi * fr);
            pr = nr; pi = ni;
        }
        float t2r[2], t2i[2];
        {   const float4 g = gmat[8];                // e bit 3
            t2r[0] = fmaf(pr,  g.x, -pi * g.y);  t2i[0] = fmaf(pr, g.y,  pi * g.x);
            t2r[1] = fmaf(pr, -g.z, -pi * g.w);  t2i[1] = fmaf(pr, g.w, -pi * g.z);
        }
        float t4r[4], t4i[4];
        {   const float4 g = gmat[9];                // e bit 2
            #pragma unroll
            for (int h = 0; h < 2; ++h) {
                t4r[2*h]   = fmaf(t2r[h],  g.x, -t2i[h] * g.y);
                t4i[2*h]   = fmaf(t2r[h],  g.y,  t2i[h] * g.x);
                t4r[2*h+1] = fmaf(t2r[h], -g.z, -t2i[h] * g.w);
                t4i[2*h+1] = fmaf(t2r[h],  g.w, -t2i[h] * g.z);
            }
        }
        float t8r[8], t8i[8];
        {   const float4 g = gmat[10];               // e bit 1
            #pragma unroll
            for (int h = 0; h < 4; ++h) {
                t8r[2*h]   = fmaf(t4r[h],  g.x, -t4i[h] * g.y);
                t8i[2*h]   = fmaf(t4r[h],  g.y,  t4i[h] * g.x);
                t8r[2*h+1] = fmaf(t4r[h], -g.z, -t4i[h] * g.w);
                t8i[2*h+1] = fmaf(t4r[h],  g.w, -t4i[h] * g.z);
            }
        }
        {   const float4 g = gmat[11];               // e bit 0
            #pragma unroll
            for (int h = 0; h < 8; ++h) {
                ar[2*h]   = fmaf(t8r[h],  g.x, -t8i[h] * g.y);
                ai[2*h]   = fmaf(t8r[h],  g.y,  t8i[h] * g.x);
                ar[2*h+1] = fmaf(t8r[h], -g.z, -t8i[h] * g.w);
                ai[2*h+1] = fmaf(t8r[h],  g.w, -t8i[h] * g.z);
            }
        }
        // write to swizzled slots: swz((tid<<4)|e) = (tid<<4) | (e ^ hh)
        const unsigned hh = ((unsigned)tid ^ ((unsigned)tid >> 4)) & 0xFu;
        const unsigned base = (unsigned)tid << 4;
        #pragma unroll
        for (int e = 0; e < 16; ++e)
            st[base | ((unsigned)e ^ hh)] = make_float2(ar[e], ai[e]);
    }
    __syncthreads();

    // ---- 9 register-blocked passes (gates 12..47) -------------------------
    unsigned jr = 0;
    run_from<0>(tid, ar, ai, jr, st, gmat);

    // ---- fused Z expvals + linear head (state still in registers) ---------
    float hws[NQ];
    #pragma unroll
    for (int w = 0; w < NQ; ++w) {
        const unsigned sg = (unsigned)(__popc(jr & PLAN.zrow[w]) & 1) << 31;
        hws[w] = xorf(hw[w], sg);
    }
    float acc = 0.0f;
    #pragma unroll
    for (int e = 0; e < 16; ++e) {
        const float prob = fmaf(ar[e], ar[e], ai[e] * ai[e]);
        float coef = 0.0f;
        #pragma unroll
        for (int w = 0; w < NQ; ++w)
            coef += ((PLAN.zparbits[w] >> e) & 1u) ? -hws[w] : hws[w];
        acc = fmaf(prob, coef, acc);
    }

    #pragma unroll
    for (int o = 32; o > 0; o >>= 1) acc += __shfl_xor(acc, o, 64);
    if ((tid & 63) == 0) red[tid >> 6] = acc;
    __syncthreads();
    if (tid == 0) out[b] = red[0] + red[1] + red[2] + red[3] + hb[0];
}

extern "C" void kernel_launch(void* const* d_in, const int* in_sizes, int n_in,
                              void* d_out, int out_size, void* d_ws, size_t ws_size,
                              hipStream_t stream) {
    const float* x  = (const float*)d_in[0];   // (B, 12) float32
    const float* W  = (const float*)d_in[1];   // (4, 12, 3) float32
    const float* hw = (const float*)d_in[2];   // (1, 12) float32
    const float* hb = (const float*)d_in[3];   // (1,) float32
    float* out = (float*)d_out;                // (B,) float32

    int B = in_sizes[0] / NQ;                  // 1024
    qreg_kernel<<<B, TPB, 0, stream>>>(x, W, hw, hb, out);
}